// Round 7
// baseline (24797.223 us; speedup 1.0000x reference)
//
#include <hip/hip_runtime.h>
#include <hip/hip_fp16.h>

static constexpr int kH   = 2048;
static constexpr int kS   = 8192;
static constexpr int kNWG = 256;
static constexpr int kTHR = 512;

typedef _Float16     h2  __attribute__((ext_vector_type(2)));
typedef unsigned int v4u __attribute__((ext_vector_type(4)));

#if __has_builtin(__builtin_amdgcn_fdot2)
__device__ __forceinline__ float FDOT2(h2 a, h2 b, float c) {
    return __builtin_amdgcn_fdot2(a, b, c, false);
}
#else
__device__ __forceinline__ float FDOT2(h2 a, h2 b, float c) {
    return (float)a[0] * (float)b[0] + (float)a[1] * (float)b[1] + c;
}
#endif
__device__ __forceinline__ h2 pk16(float lo, float hi) {
    return __builtin_bit_cast(h2, __builtin_amdgcn_cvt_pkrtz(lo, hi));
}

// MALL-coherent poll: 4 x dwordx4 (records i, i+64, i+128, i+192), one drain.
__device__ __forceinline__ void poll4(const void* p, v4u& a, v4u& b, v4u& c, v4u& d) {
    asm volatile("global_load_dwordx4 %0, %4, off sc0 sc1\n\t"
                 "global_load_dwordx4 %1, %4, off offset:1024 sc0 sc1\n\t"
                 "global_load_dwordx4 %2, %4, off offset:2048 sc0 sc1\n\t"
                 "global_load_dwordx4 %3, %4, off offset:3072 sc0 sc1\n\t"
                 "s_waitcnt vmcnt(0)"
                 : "=&v"(a), "=&v"(b), "=&v"(c), "=&v"(d) : "v"(p) : "memory");
}
// 2-byte MALL-coherent store: one wave's h element, toggle in f16 LSB.
__device__ __forceinline__ void store2_coh(void* p, unsigned int v) {
    asm volatile("global_store_short %0, %1, off sc0 sc1"
                 :: "v"(p), "v"(v) : "memory");
}

// Persistent GRU. 256 WGs x 512 threads (8 waves), one WG per CU.
// Wave wv owns element e = wg*8+wv; lane l covers cols 4l+256m+k (m<8,k<4).
// Publish: lane0 of each wave stores h[e] as f16 with toggle(s)=((s>>1)^s)&1
// in the LSB, straight to record slot[s&1] (2 B, sc0 sc1). No LDS round, no
// trailing barrier. Reader validates all 8 LSBs per 16 B record; detect loads
// ARE the data. LDS h is double-buffered -> ONE __syncthreads per step.
__global__ __launch_bounds__(kTHR, 2)
void gru_persistent(const float* __restrict__ x,    // [S,H] f32
                    const float* __restrict__ Wih,  // [3H,H] f32
                    const float* __restrict__ Whh,  // [3H,H] f32
                    const float* __restrict__ bih,  // [3H] f32
                    const float* __restrict__ bhh,  // [3H] f32
                    float* __restrict__ out,        // [H] f32
                    unsigned char* __restrict__ rec) // 2 slots * 4096 B (zeroed)
{
    __shared__ __align__(16) unsigned short hlds[2][kH];  // f16 h, double-buffered

    const int wg  = blockIdx.x;
    const int tid = threadIdx.x;
    const int wv  = tid >> 6;      // 0..7
    const int l   = tid & 63;      // 0..63
    const int e   = wg * 8 + wv;
    const int cb  = 4 * l;

    // Weights as f16 pairs: Wih 48 regs + Whh 48 regs.
    h2 wih[3][8][2], whh[3][8][2];
#pragma unroll
    for (int G = 0; G < 3; ++G) {
        const size_t row = (size_t)(G * kH + e) * kH;
#pragma unroll
        for (int m = 0; m < 8; ++m) {
            const size_t off = row + cb + 256 * m;
            const float4 wi = *(const float4*)(Wih + off);
            const float4 wh = *(const float4*)(Whh + off);
            wih[G][m][0] = pk16(wi.x, wi.y);  wih[G][m][1] = pk16(wi.z, wi.w);
            whh[G][m][0] = pk16(wh.x, wh.y);  whh[G][m][1] = pk16(wh.z, wh.w);
        }
    }
    const float bir  = bih[e];
    const float biz  = bih[kH + e];
    const float bin_ = bih[2 * kH + e];
    const float bhr  = bhh[e];
    const float bhz  = bhh[kH + e];
    const float bhn  = bhh[2 * kH + e];

    // Software-pipelined x row (row t+1 loads issue while step t syncs/computes).
    float4 xpf[8];
#pragma unroll
    for (int m = 0; m < 8; ++m)
        xpf[m] = *(const float4*)(x + cb + 256 * m);

    float hold = 0.0f;  // h for element e (valid on lane 0 of wave wv)

#pragma unroll 1
    for (int t = 0; t < kS; ++t) {
        // ---- x projection from prefetched registers (pure VALU, ~64 dot2) ----
        float ar = 0.f, az = 0.f, an = 0.f;
#pragma unroll
        for (int m = 0; m < 8; ++m) {
            const h2 x0 = pk16(xpf[m].x, xpf[m].y);
            const h2 x1 = pk16(xpf[m].z, xpf[m].w);
            ar = FDOT2(wih[0][m][0], x0, ar); ar = FDOT2(wih[0][m][1], x1, ar);
            az = FDOT2(wih[1][m][0], x0, az); az = FDOT2(wih[1][m][1], x1, az);
            an = FDOT2(wih[2][m][0], x0, an); an = FDOT2(wih[2][m][1], x1, an);
        }
        // issue next row's loads now; they fill during poll/sync/h-proj
        if (t + 1 < kS) {
            const float* xn = x + (size_t)(t + 1) * kH;
#pragma unroll
            for (int m = 0; m < 8; ++m)
                xpf[m] = *(const float4*)(xn + cb + 256 * m);
        }

        // ---- wave 0: poll records for step-t toggles; payload = h_t ----
        if (tid < 64) {
            if (t > 0) {
                const unsigned int tg = (unsigned int)(((t >> 1) ^ t) & 1);
                const unsigned int tp = tg * 0x00010001u;
                const char* base = (const char*)rec + (t & 1) * 4096 + tid * 16;
                v4u r0, r1, r2, r3;
                for (;;) {
                    poll4(base, r0, r1, r2, r3);
                    const unsigned int bad =
                        ((r0.x ^ tp) | (r0.y ^ tp) | (r0.z ^ tp) | (r0.w ^ tp) |
                         (r1.x ^ tp) | (r1.y ^ tp) | (r1.z ^ tp) | (r1.w ^ tp) |
                         (r2.x ^ tp) | (r2.y ^ tp) | (r2.z ^ tp) | (r2.w ^ tp) |
                         (r3.x ^ tp) | (r3.y ^ tp) | (r3.z ^ tp) | (r3.w ^ tp))
                        & 0x00010001u;
                    if (__all(bad == 0u)) break;
                }
                unsigned short* hb = hlds[t & 1];
                *(v4u*)&hb[tid * 8]         = r0;
                *(v4u*)&hb[(tid + 64) * 8]  = r1;
                *(v4u*)&hb[(tid + 128) * 8] = r2;
                *(v4u*)&hb[(tid + 192) * 8] = r3;
            } else {
                unsigned short* hb = hlds[0];
                const v4u z = {0u, 0u, 0u, 0u};
                *(v4u*)&hb[tid * 8]         = z;
                *(v4u*)&hb[(tid + 64) * 8]  = z;
                *(v4u*)&hb[(tid + 128) * 8] = z;
                *(v4u*)&hb[(tid + 192) * 8] = z;
            }
        }
        __syncthreads();  // the ONLY barrier per step

        // ---- h projection from LDS f16 (b64 lane-contiguous, conflict-free) ----
        float hr = 0.f, hz = 0.f, hn = 0.f;
        const unsigned short* hb = hlds[t & 1];
#pragma unroll
        for (int m = 0; m < 8; ++m) {
            const uint2 hu = *(const uint2*)&hb[cb + 256 * m];
            const h2 h0 = __builtin_bit_cast(h2, hu.x);
            const h2 h1 = __builtin_bit_cast(h2, hu.y);
            hr = FDOT2(whh[0][m][0], h0, hr); hr = FDOT2(whh[0][m][1], h1, hr);
            hz = FDOT2(whh[1][m][0], h0, hz); hz = FDOT2(whh[1][m][1], h1, hz);
            hn = FDOT2(whh[2][m][0], h0, hn); hn = FDOT2(whh[2][m][1], h1, hn);
        }

        // ---- wave-wide reduce to lane 0 ----
        float pr = ar + hr, pz = az + hz, pxn = an, phn = hn;
#pragma unroll
        for (int m = 32; m >= 1; m >>= 1) {
            pr  += __shfl_xor(pr,  m, 64);
            pz  += __shfl_xor(pz,  m, 64);
            pxn += __shfl_xor(pxn, m, 64);
            phn += __shfl_xor(phn, m, 64);
        }

        // ---- gates + direct publish (lane 0 of each wave, 2 B store) ----
        if (l == 0) {
            const float r = 1.f / (1.f + __expf(-(pr + bir + bhr)));
            const float z = 1.f / (1.f + __expf(-(pz + biz + bhz)));
            const float a = (pxn + bin_) + r * (phn + bhn);
            const float ee = __expf(-2.f * fabsf(a));
            float th = (1.f - ee) / (1.f + ee);
            th = (a < 0.f) ? -th : th;
            hold = (1.f - z) * th + z * hold;

            const __half hh = __float2half(hold);
            unsigned int hv = *(const unsigned short*)&hh;
            const unsigned int tg1 = (unsigned int)((((t + 1) >> 1) ^ (t + 1)) & 1);
            hv = (hv & ~1u) | tg1;
            store2_coh((char*)rec + ((t + 1) & 1) * 4096 + wg * 16 + wv * 2, hv);
        }
    }

    if (l == 0)
        out[e] = hold;
}

extern "C" void kernel_launch(void* const* d_in, const int* in_sizes, int n_in,
                              void* d_out, int out_size, void* d_ws, size_t ws_size,
                              hipStream_t stream) {
    (void)in_sizes; (void)n_in; (void)out_size; (void)ws_size;
    const float* x   = (const float*)d_in[0];
    const float* Wih = (const float*)d_in[1];
    const float* Whh = (const float*)d_in[2];
    const float* bih = (const float*)d_in[3];
    const float* bhh = (const float*)d_in[4];

    unsigned char* rec = (unsigned char*)d_ws;   // 2 slots * 4096 B
    (void)hipMemsetAsync(rec, 0, 8192, stream);  // h_0 = 0 (slot0 toggle 0); slot1 blocks
    gru_persistent<<<dim3(kNWG), dim3(kTHR), 0, stream>>>(
        x, Wih, Whh, bih, bhh, (float*)d_out, rec);
}